// Round 1
// baseline (3430.569 us; speedup 1.0000x reference)
//
#include <hip/hip_runtime.h>
#include <hip/hip_bf16.h>

// Problem constants (from reference)
#define N_NODES 10000
#define N_EDGES 640000
#define IN_DIM  128
#define HID_DIM 256
#define OUT_DIM 128

// ---------------------------------------------------------------------------
// Degree: one atomic per edge
// ---------------------------------------------------------------------------
__global__ void deg_kernel(const int* __restrict__ dst, float* __restrict__ deg, int E) {
    int e = blockIdx.x * blockDim.x + threadIdx.x;
    if (e < E) atomicAdd(&deg[dst[e]], 1.0f);
}

// ---------------------------------------------------------------------------
// Scatter-add of source features to destination accumulator.
// D = feature dim (multiple of 4). One thread handles one (edge, 4-dim chunk).
// Consecutive threads in a wave -> same/adjacent edges, coalesced float4 reads.
// ---------------------------------------------------------------------------
template<int D>
__global__ void scatter_kernel(const float* __restrict__ feat,
                               const int*   __restrict__ src,
                               const int*   __restrict__ dst,
                               float*       __restrict__ out,
                               int E) {
    const int LANES = D / 4;
    const int total = E * LANES;
    int gid    = blockIdx.x * blockDim.x + threadIdx.x;
    int stride = gridDim.x * blockDim.x;
    for (int i = gid; i < total; i += stride) {
        int e = i / LANES;       // power-of-two -> shift
        int l = i & (LANES - 1);
        int s = src[e];
        int d = dst[e];
        float4 v = ((const float4*)(feat + s * D))[l];
        float* o = out + d * D + l * 4;
        atomicAdd(o + 0, v.x);
        atomicAdd(o + 1, v.y);
        atomicAdd(o + 2, v.z);
        atomicAdd(o + 3, v.w);
    }
}

// ---------------------------------------------------------------------------
// Fused SAGE linear: out[n][j] = act( (agg[n]/max(deg,1)) . W_l[:,j] + b[j]
//                                     + self[n] . W_r[:,j] )
// K = input dim, J = output dim (= blockDim.x), NB = nodes per block.
// Rows staged in LDS (broadcast reads), W reads coalesced across j.
// ---------------------------------------------------------------------------
template<int K, int J, int NB>
__global__ void sage_linear_kernel(const float* __restrict__ agg,
                                   const float* __restrict__ self_feat,
                                   const float* __restrict__ deg,
                                   const float* __restrict__ W_l,
                                   const float* __restrict__ b,
                                   const float* __restrict__ W_r,
                                   float*       __restrict__ out,
                                   int N, int relu) {
    __shared__ float sa[NB][K];
    __shared__ float sx[NB][K];
    const int n0  = blockIdx.x * NB;
    const int tid = threadIdx.x;   // 0..J-1

    // Cooperative load of NB rows (agg scaled by 1/deg, and self features)
    for (int i = tid; i < NB * K; i += J) {
        int r = i / K;       // power-of-two
        int c = i & (K - 1);
        int n = n0 + r;
        float a = 0.0f, xv = 0.0f;
        if (n < N) {
            float dinv = 1.0f / fmaxf(deg[n], 1.0f);
            a  = agg[n * K + c] * dinv;
            xv = self_feat[n * K + c];
        }
        sa[r][c] = a;
        sx[r][c] = xv;
    }
    __syncthreads();

    float acc[NB];
    const float bb = b[tid];
#pragma unroll
    for (int r = 0; r < NB; ++r) acc[r] = bb;

    for (int k = 0; k < K; ++k) {
        float wl = W_l[k * J + tid];
        float wr = W_r[k * J + tid];
#pragma unroll
        for (int r = 0; r < NB; ++r) {
            acc[r] += sa[r][k] * wl + sx[r][k] * wr;
        }
    }

#pragma unroll
    for (int r = 0; r < NB; ++r) {
        int n = n0 + r;
        if (n < N) {
            float v = acc[r];
            if (relu) v = fmaxf(v, 0.0f);
            out[n * J + tid] = v;
        }
    }
}

// ---------------------------------------------------------------------------
// Launch
// ---------------------------------------------------------------------------
extern "C" void kernel_launch(void* const* d_in, const int* in_sizes, int n_in,
                              void* d_out, int out_size, void* d_ws, size_t ws_size,
                              hipStream_t stream) {
    const float* x    = (const float*)d_in[0];
    const int*   ei   = (const int*)  d_in[1];   // (2, E): [0]=src row, [1]=dst row
    const float* W1_l = (const float*)d_in[2];
    const float* b1   = (const float*)d_in[3];
    const float* W1_r = (const float*)d_in[4];
    const float* W2_l = (const float*)d_in[5];
    const float* b2   = (const float*)d_in[6];
    const float* W2_r = (const float*)d_in[7];
    float* out = (float*)d_out;

    const int* src = ei;
    const int* dst = ei + N_EDGES;

    // Workspace layout (floats)
    float* ws   = (float*)d_ws;
    float* deg  = ws;                          // 10240 (padded)
    float* agg1 = deg  + 10240;                // N_NODES * IN_DIM  = 1,280,000
    float* h    = agg1 + N_NODES * IN_DIM;     // N_NODES * HID_DIM = 2,560,000
    float* agg2 = h    + N_NODES * HID_DIM;    // N_NODES * HID_DIM = 2,560,000

    // Zero deg + agg1 (contiguous) and agg2
    hipMemsetAsync(deg,  0, (10240 + (size_t)N_NODES * IN_DIM) * sizeof(float), stream);
    hipMemsetAsync(agg2, 0, (size_t)N_NODES * HID_DIM * sizeof(float), stream);

    // Degree (shared by both layers)
    deg_kernel<<<(N_EDGES + 255) / 256, 256, 0, stream>>>(dst, deg, N_EDGES);

    // Layer 1: scatter x, then fused linear + ReLU
    scatter_kernel<IN_DIM><<<4096, 256, 0, stream>>>(x, src, dst, agg1, N_EDGES);
    sage_linear_kernel<IN_DIM, HID_DIM, 8>
        <<<(N_NODES + 7) / 8, HID_DIM, 0, stream>>>(agg1, x, deg, W1_l, b1, W1_r, h,
                                                    N_NODES, 1);

    // Layer 2: scatter h, then fused linear (no activation)
    scatter_kernel<HID_DIM><<<8192, 256, 0, stream>>>(h, src, dst, agg2, N_EDGES);
    sage_linear_kernel<HID_DIM, OUT_DIM, 8>
        <<<(N_NODES + 7) / 8, OUT_DIM, 0, stream>>>(agg2, h, deg, W2_l, b2, W2_r, out,
                                                    N_NODES, 0);
}

// Round 2
// 335.524 us; speedup vs baseline: 10.2245x; 10.2245x over previous
//
#include <hip/hip_runtime.h>
#include <hip/hip_bf16.h>

// Problem constants (from reference)
#define N_NODES 10000
#define N_EDGES 640000
#define IN_DIM  128
#define HID_DIM 256
#define OUT_DIM 128

// ---------------------------------------------------------------------------
// CSR build step 1: int histogram of destination degrees
// ---------------------------------------------------------------------------
__global__ void hist_kernel(const int* __restrict__ dst, int* __restrict__ deg, int E) {
    int e = blockIdx.x * blockDim.x + threadIdx.x;
    if (e < E) atomicAdd(&deg[dst[e]], 1);
}

// ---------------------------------------------------------------------------
// CSR build step 2: single-block exclusive scan -> rowptr (n+1 entries),
// and initialize cursor[n] = rowptr[n] for the fill pass.
// ---------------------------------------------------------------------------
__global__ void scan_kernel(const int* __restrict__ deg,
                            int* __restrict__ rowptr,
                            int* __restrict__ cursor, int n) {
    __shared__ int part[256];
    const int tid = threadIdx.x;
    const int CH  = (n + 255) / 256;   // elements per thread
    const int base = tid * CH;

    int s = 0;
    for (int i = 0; i < CH; ++i) {
        int idx = base + i;
        if (idx < n) s += deg[idx];
    }
    part[tid] = s;
    __syncthreads();
    // Hillis-Steele inclusive scan over 256 partials
    for (int off = 1; off < 256; off <<= 1) {
        int v = (tid >= off) ? part[tid - off] : 0;
        __syncthreads();
        part[tid] += v;
        __syncthreads();
    }
    int run = (tid == 0) ? 0 : part[tid - 1];
    for (int i = 0; i < CH; ++i) {
        int idx = base + i;
        if (idx < n) {
            rowptr[idx] = run;
            cursor[idx] = run;
            run += deg[idx];
        }
    }
    if (tid == 255) rowptr[n] = run;   // total = E
}

// ---------------------------------------------------------------------------
// CSR build step 3: scatter edge sources into dst-sorted order (int atomics)
// ---------------------------------------------------------------------------
__global__ void fill_kernel(const int* __restrict__ src, const int* __restrict__ dst,
                            int* __restrict__ cursor, int* __restrict__ esrc, int E) {
    int e = blockIdx.x * blockDim.x + threadIdx.x;
    if (e < E) {
        int d   = dst[e];
        int pos = atomicAdd(&cursor[d], 1);
        esrc[pos] = src[e];
    }
}

// ---------------------------------------------------------------------------
// Gather-mean: one wave (64 threads) per node, each lane owns 2 feature dims.
// D must be 128. Reads are coalesced 512B/wave per neighbor row; no atomics.
// ---------------------------------------------------------------------------
template<int D>
__global__ void gather_mean_kernel(const float* __restrict__ feat,
                                   const int*   __restrict__ rowptr,
                                   const int*   __restrict__ esrc,
                                   float*       __restrict__ out) {
    const int n = blockIdx.x;
    const int t = threadIdx.x;           // 0..63
    const int beg = rowptr[n], end = rowptr[n + 1];

    float ax = 0.0f, ay = 0.0f;
    int e = beg;
    for (; e + 3 < end; e += 4) {
        int s0 = esrc[e + 0], s1 = esrc[e + 1], s2 = esrc[e + 2], s3 = esrc[e + 3];
        float2 v0 = *(const float2*)(feat + s0 * D + 2 * t);
        float2 v1 = *(const float2*)(feat + s1 * D + 2 * t);
        float2 v2 = *(const float2*)(feat + s2 * D + 2 * t);
        float2 v3 = *(const float2*)(feat + s3 * D + 2 * t);
        ax += v0.x + v1.x + v2.x + v3.x;
        ay += v0.y + v1.y + v2.y + v3.y;
    }
    for (; e < end; ++e) {
        float2 v = *(const float2*)(feat + esrc[e] * D + 2 * t);
        ax += v.x; ay += v.y;
    }
    const float dinv = (end > beg) ? 1.0f / (float)(end - beg) : 0.0f;
    float2 r; r.x = ax * dinv; r.y = ay * dinv;
    *(float2*)(out + n * D + 2 * t) = r;
}

// ---------------------------------------------------------------------------
// Fused SAGE linear: out[n][j] = act( agg[n].W_l[:,j] + b[j] + x[n].W_r[:,j] )
// agg is already mean-normalized. J = blockDim.x, NB nodes per block.
// ---------------------------------------------------------------------------
template<int K, int J, int NB>
__global__ void sage_linear_kernel(const float* __restrict__ agg,
                                   const float* __restrict__ self_feat,
                                   const float* __restrict__ W_l,
                                   const float* __restrict__ b,
                                   const float* __restrict__ W_r,
                                   float*       __restrict__ out,
                                   int N, int relu) {
    __shared__ float sa[NB][K];
    __shared__ float sx[NB][K];
    const int n0  = blockIdx.x * NB;
    const int tid = threadIdx.x;

    for (int i = tid; i < NB * K; i += J) {
        int r = i / K;
        int c = i & (K - 1);
        int n = n0 + r;
        sa[r][c] = (n < N) ? agg[n * K + c] : 0.0f;
        sx[r][c] = (n < N) ? self_feat[n * K + c] : 0.0f;
    }
    __syncthreads();

    float acc[NB];
    const float bb = b[tid];
#pragma unroll
    for (int r = 0; r < NB; ++r) acc[r] = bb;

    for (int k = 0; k < K; ++k) {
        float wl = W_l[k * J + tid];
        float wr = W_r[k * J + tid];
#pragma unroll
        for (int r = 0; r < NB; ++r)
            acc[r] += sa[r][k] * wl + sx[r][k] * wr;
    }

#pragma unroll
    for (int r = 0; r < NB; ++r) {
        int n = n0 + r;
        if (n < N) {
            float v = acc[r];
            if (relu) v = fmaxf(v, 0.0f);
            out[n * J + tid] = v;
        }
    }
}

// ---------------------------------------------------------------------------
// Plain GEMM: out[n][j] = x[n] . W[:,j]     (for p = h @ W2_l projection)
// ---------------------------------------------------------------------------
template<int K, int J, int NB>
__global__ void gemm_kernel(const float* __restrict__ x,
                            const float* __restrict__ W,
                            float*       __restrict__ out, int N) {
    __shared__ float sx[NB][K];
    const int n0  = blockIdx.x * NB;
    const int tid = threadIdx.x;

    for (int i = tid; i < NB * K; i += J) {
        int r = i / K;
        int c = i & (K - 1);
        int n = n0 + r;
        sx[r][c] = (n < N) ? x[n * K + c] : 0.0f;
    }
    __syncthreads();

    float acc[NB];
#pragma unroll
    for (int r = 0; r < NB; ++r) acc[r] = 0.0f;

    for (int k = 0; k < K; ++k) {
        float w = W[k * J + tid];
#pragma unroll
        for (int r = 0; r < NB; ++r)
            acc[r] += sx[r][k] * w;
    }

#pragma unroll
    for (int r = 0; r < NB; ++r) {
        int n = n0 + r;
        if (n < N) out[n * J + tid] = acc[r];
    }
}

// ---------------------------------------------------------------------------
// Final combine: out[n][j] = pre[n][j] + b[j] + x[n] . W[:,j]
// (pre = gather-mean of projected features q)
// ---------------------------------------------------------------------------
template<int K, int J, int NB>
__global__ void final_kernel(const float* __restrict__ pre,
                             const float* __restrict__ x,
                             const float* __restrict__ W,
                             const float* __restrict__ b,
                             float*       __restrict__ out, int N) {
    __shared__ float sx[NB][K];
    const int n0  = blockIdx.x * NB;
    const int tid = threadIdx.x;

    for (int i = tid; i < NB * K; i += J) {
        int r = i / K;
        int c = i & (K - 1);
        int n = n0 + r;
        sx[r][c] = (n < N) ? x[n * K + c] : 0.0f;
    }
    __syncthreads();

    float acc[NB];
    const float bb = b[tid];
#pragma unroll
    for (int r = 0; r < NB; ++r) acc[r] = bb;

    for (int k = 0; k < K; ++k) {
        float w = W[k * J + tid];
#pragma unroll
        for (int r = 0; r < NB; ++r)
            acc[r] += sx[r][k] * w;
    }

#pragma unroll
    for (int r = 0; r < NB; ++r) {
        int n = n0 + r;
        if (n < N) out[n * J + tid] = acc[r] + pre[n * J + tid];
    }
}

// ---------------------------------------------------------------------------
// Launch
// ---------------------------------------------------------------------------
extern "C" void kernel_launch(void* const* d_in, const int* in_sizes, int n_in,
                              void* d_out, int out_size, void* d_ws, size_t ws_size,
                              hipStream_t stream) {
    const float* x    = (const float*)d_in[0];
    const int*   ei   = (const int*)  d_in[1];   // (2, E): row 0 = src, row 1 = dst
    const float* W1_l = (const float*)d_in[2];
    const float* b1   = (const float*)d_in[3];
    const float* W1_r = (const float*)d_in[4];
    const float* W2_l = (const float*)d_in[5];
    const float* b2   = (const float*)d_in[6];
    const float* W2_r = (const float*)d_in[7];
    float* out = (float*)d_out;

    const int* src = ei;
    const int* dst = ei + N_EDGES;

    // ---- workspace layout ----
    int* ip       = (int*)d_ws;
    int* deg_i    = ip;                 // 10240
    int* rowptr   = ip + 10240;         // 10241 (padded to 10496)
    int* cursor   = ip + 20736;         // 10240
    int* esrc     = ip + 30976;         // 640000
    float* fp     = (float*)(ip + 670976);
    float* agg1   = fp;                              // 1,280,000  (reused as p)
    float* h      = fp + 1280000;                    // 2,560,000
    float* q      = fp + 3840000;                    // 1,280,000
    float* p      = agg1;   // safe: agg1 dead before p is written

    // ---- CSR build (int atomics only) ----
    hipMemsetAsync(deg_i, 0, 10240 * sizeof(int), stream);
    hist_kernel<<<(N_EDGES + 255) / 256, 256, 0, stream>>>(dst, deg_i, N_EDGES);
    scan_kernel<<<1, 256, 0, stream>>>(deg_i, rowptr, cursor, N_NODES);
    fill_kernel<<<(N_EDGES + 255) / 256, 256, 0, stream>>>(src, dst, cursor, esrc, N_EDGES);

    // ---- Layer 1: gather-mean(x) -> agg1; h = relu(agg1@W1_l + b1 + x@W1_r) ----
    gather_mean_kernel<IN_DIM><<<N_NODES, 64, 0, stream>>>(x, rowptr, esrc, agg1);
    sage_linear_kernel<IN_DIM, HID_DIM, 8>
        <<<(N_NODES + 7) / 8, HID_DIM, 0, stream>>>(agg1, x, W1_l, b1, W1_r, h, N_NODES, 1);

    // ---- Layer 2 (projection trick: mean(h)@W2_l == mean(h@W2_l)) ----
    gemm_kernel<HID_DIM, OUT_DIM, 8>
        <<<(N_NODES + 7) / 8, OUT_DIM, 0, stream>>>(h, W2_l, p, N_NODES);
    gather_mean_kernel<OUT_DIM><<<N_NODES, 64, 0, stream>>>(p, rowptr, esrc, q);
    final_kernel<HID_DIM, OUT_DIM, 8>
        <<<(N_NODES + 7) / 8, OUT_DIM, 0, stream>>>(q, h, W2_r, b2, out, N_NODES);
}

// Round 3
// 244.624 us; speedup vs baseline: 14.0238x; 1.3716x over previous
//
#include <hip/hip_runtime.h>
#include <hip/hip_bf16.h>

#define N_NODES 10000
#define N_EDGES 640000
#define IN_DIM  128
#define HID_DIM 256
#define OUT_DIM 128

typedef __attribute__((ext_vector_type(8))) short short8;
typedef __attribute__((ext_vector_type(4))) float float4v;
typedef unsigned short ushort_t;
typedef unsigned int uint_t;

// round-to-nearest-even fp32 -> bf16 bits
__device__ inline ushort_t f2bf(float f) {
    uint_t u = __float_as_uint(f);
    u += 0x7fffu + ((u >> 16) & 1u);
    return (ushort_t)(u >> 16);
}
__device__ inline float bf_lo(uint_t u) { return __uint_as_float(u << 16); }
__device__ inline float bf_hi(uint_t u) { return __uint_as_float(u & 0xffff0000u); }

// ---------------------------------------------------------------------------
// CSR build (int atomics only)
// ---------------------------------------------------------------------------
__global__ void hist_kernel(const int* __restrict__ dst, int* __restrict__ deg, int E) {
    int e = blockIdx.x * blockDim.x + threadIdx.x;
    if (e < E) atomicAdd(&deg[dst[e]], 1);
}

__global__ void scan_kernel(const int* __restrict__ deg,
                            int* __restrict__ rowptr,
                            int* __restrict__ cursor, int n) {
    __shared__ int part[256];
    const int tid = threadIdx.x;
    const int CH  = (n + 255) / 256;
    const int base = tid * CH;
    int s = 0;
    for (int i = 0; i < CH; ++i) {
        int idx = base + i;
        if (idx < n) s += deg[idx];
    }
    part[tid] = s;
    __syncthreads();
    for (int off = 1; off < 256; off <<= 1) {
        int v = (tid >= off) ? part[tid - off] : 0;
        __syncthreads();
        part[tid] += v;
        __syncthreads();
    }
    int run = (tid == 0) ? 0 : part[tid - 1];
    for (int i = 0; i < CH; ++i) {
        int idx = base + i;
        if (idx < n) {
            rowptr[idx] = run;
            cursor[idx] = run;
            run += deg[idx];
        }
    }
    if (tid == 255) rowptr[n] = run;
}

__global__ void fill_kernel(const int* __restrict__ src, const int* __restrict__ dst,
                            int* __restrict__ cursor, int* __restrict__ esrc, int E) {
    int e = blockIdx.x * blockDim.x + threadIdx.x;
    if (e < E) {
        int d   = dst[e];
        int pos = atomicAdd(&cursor[d], 1);
        esrc[pos] = src[e];
    }
}

// ---------------------------------------------------------------------------
// Prep: x -> bf16; weights -> transposed bf16 (Wt[n][k]) for contiguous
// B-fragment loads. w1t stacks [W1_l ; W1_r] along K (256 rows of K).
// ---------------------------------------------------------------------------
#define PREP_X   (N_NODES * IN_DIM)                       // 1,280,000
#define PREP_W1  (HID_DIM * (2 * IN_DIM))                 //    65,536
#define PREP_W2  (OUT_DIM * HID_DIM)                      //    32,768
#define PREP_TOTAL (PREP_X + PREP_W1 + 2 * PREP_W2)

__global__ void prep_kernel(const float* __restrict__ x,
                            const float* __restrict__ W1_l, const float* __restrict__ W1_r,
                            const float* __restrict__ W2_l, const float* __restrict__ W2_r,
                            ushort_t* __restrict__ xb,  ushort_t* __restrict__ w1t,
                            ushort_t* __restrict__ w2tl, ushort_t* __restrict__ w2tr) {
    int i = blockIdx.x * blockDim.x + threadIdx.x;
    if (i < PREP_X) {
        xb[i] = f2bf(x[i]);
    } else if (i < PREP_X + PREP_W1) {
        int j = i - PREP_X;
        int n = j >> 8, k = j & 255;            // w1t[n][k], n in [0,256)
        float v = (k < 128) ? W1_l[k * HID_DIM + n] : W1_r[(k - 128) * HID_DIM + n];
        w1t[j] = f2bf(v);
    } else if (i < PREP_X + PREP_W1 + PREP_W2) {
        int j = i - (PREP_X + PREP_W1);
        int n = j >> 8, k = j & 255;            // w2tl[n][k], n in [0,128)
        w2tl[j] = f2bf(W2_l[k * OUT_DIM + n]);
    } else if (i < PREP_TOTAL) {
        int j = i - (PREP_X + PREP_W1 + PREP_W2);
        int n = j >> 8, k = j & 255;
        w2tr[j] = f2bf(W2_r[k * OUT_DIM + n]);
    }
}

// ---------------------------------------------------------------------------
// Gather-mean over bf16 rows (D=128 -> 64 uints/row). One wave per node,
// lane t owns dims {2t, 2t+1}. fp32 accumulate, bf16 output.
// ---------------------------------------------------------------------------
__global__ void gather_mean_bf16(const ushort_t* __restrict__ feat,
                                 const int* __restrict__ rowptr,
                                 const int* __restrict__ esrc,
                                 ushort_t* __restrict__ out) {
    const uint_t* f = (const uint_t*)feat;
    const int n = blockIdx.x;
    const int t = threadIdx.x;                   // 0..63
    const int beg = rowptr[n], end = rowptr[n + 1];

    float ax = 0.0f, ay = 0.0f;
    int e = beg;
    for (; e + 3 < end; e += 4) {
        uint_t u0 = f[esrc[e + 0] * 64 + t];
        uint_t u1 = f[esrc[e + 1] * 64 + t];
        uint_t u2 = f[esrc[e + 2] * 64 + t];
        uint_t u3 = f[esrc[e + 3] * 64 + t];
        ax += bf_lo(u0) + bf_lo(u1) + bf_lo(u2) + bf_lo(u3);
        ay += bf_hi(u0) + bf_hi(u1) + bf_hi(u2) + bf_hi(u3);
    }
    for (; e < end; ++e) {
        uint_t u = f[esrc[e] * 64 + t];
        ax += bf_lo(u); ay += bf_hi(u);
    }
    const float dinv = (end > beg) ? 1.0f / (float)(end - beg) : 0.0f;
    uint_t packed = (uint_t)f2bf(ax * dinv) | ((uint_t)f2bf(ay * dinv) << 16);
    ((uint_t*)out)[n * 64 + t] = packed;
}

// ---------------------------------------------------------------------------
// Final gather + epilogue: out[n][:] = mean_e P[src[e]][:] + R[n][:] + b2
// ---------------------------------------------------------------------------
__global__ void gather_final(const ushort_t* __restrict__ Pb,
                             const int* __restrict__ rowptr,
                             const int* __restrict__ esrc,
                             const float* __restrict__ Rf,
                             const float* __restrict__ b2,
                             float* __restrict__ out) {
    const uint_t* f = (const uint_t*)Pb;
    const int n = blockIdx.x;
    const int t = threadIdx.x;
    const int beg = rowptr[n], end = rowptr[n + 1];

    float ax = 0.0f, ay = 0.0f;
    int e = beg;
    for (; e + 3 < end; e += 4) {
        uint_t u0 = f[esrc[e + 0] * 64 + t];
        uint_t u1 = f[esrc[e + 1] * 64 + t];
        uint_t u2 = f[esrc[e + 2] * 64 + t];
        uint_t u3 = f[esrc[e + 3] * 64 + t];
        ax += bf_lo(u0) + bf_lo(u1) + bf_lo(u2) + bf_lo(u3);
        ay += bf_hi(u0) + bf_hi(u1) + bf_hi(u2) + bf_hi(u3);
    }
    for (; e < end; ++e) {
        uint_t u = f[esrc[e] * 64 + t];
        ax += bf_lo(u); ay += bf_hi(u);
    }
    const float dinv = (end > beg) ? 1.0f / (float)(end - beg) : 0.0f;
    float2 r = *(const float2*)(Rf + n * OUT_DIM + 2 * t);
    float2 o;
    o.x = ax * dinv + r.x + b2[2 * t];
    o.y = ay * dinv + r.y + b2[2 * t + 1];
    *(float2*)(out + n * OUT_DIM + 2 * t) = o;
}

// ---------------------------------------------------------------------------
// MFMA layer 1: h[10000][256] = relu( [agg|x] @ [W1_l;W1_r] + b1 ), bf16 out.
// One wave per (16-row slab, 128-col half). K = 256 (concat of agg,x).
// A-frag: A[m=lane&15][k=q*8+j]; B-frag: Wt[n=lane&15][k=q*8+j];
// C/D: col=lane&15, row=q*4+reg (m89-verified layouts).
// ---------------------------------------------------------------------------
__global__ void mfma1_kernel(const ushort_t* __restrict__ aggb,
                             const ushort_t* __restrict__ xb,
                             const ushort_t* __restrict__ w1t,
                             const float* __restrict__ b1,
                             ushort_t* __restrict__ hb) {
    const int wrow = blockIdx.x * 16;
    const int half = blockIdx.y;              // 0/1 -> cols [half*128, +128)
    const int l = threadIdx.x;
    const int m = l & 15, q = l >> 4;

    float4v acc[8];
#pragma unroll
    for (int t = 0; t < 8; ++t) acc[t] = (float4v){0.f, 0.f, 0.f, 0.f};

    const ushort_t* arow_a = aggb + (wrow + m) * IN_DIM + q * 8;
    const ushort_t* arow_x = xb   + (wrow + m) * IN_DIM + q * 8;
    const ushort_t* bbase  = w1t + (half * 128 + m) * 256 + q * 8;

#pragma unroll
    for (int s = 0; s < 8; ++s) {
        const ushort_t* ap = (s < 4) ? (arow_a + s * 32) : (arow_x + (s - 4) * 32);
        short8 a = *(const short8*)ap;
#pragma unroll
        for (int t = 0; t < 8; ++t) {
            short8 b = *(const short8*)(bbase + (t * 16) * 256 + s * 32);
            acc[t] = __builtin_amdgcn_mfma_f32_16x16x32_bf16(a, b, acc[t], 0, 0, 0);
        }
    }

#pragma unroll
    for (int t = 0; t < 8; ++t) {
        int col = half * 128 + t * 16 + m;
        float bv = b1[col];
#pragma unroll
        for (int r = 0; r < 4; ++r) {
            int row = wrow + q * 4 + r;
            float v = acc[t][r] + bv;
            v = fmaxf(v, 0.0f);
            hb[row * HID_DIM + col] = f2bf(v);
        }
    }
}

// ---------------------------------------------------------------------------
// MFMA layer 2: which=0 -> Pb = h @ W2_l (bf16); which=1 -> Rf = h @ W2_r (fp32)
// K = 256, N = 128 (8 tiles per wave).
// ---------------------------------------------------------------------------
__global__ void mfma2_kernel(const ushort_t* __restrict__ hb,
                             const ushort_t* __restrict__ w2tl,
                             const ushort_t* __restrict__ w2tr,
                             ushort_t* __restrict__ Pb,
                             float* __restrict__ Rf) {
    const int wrow = blockIdx.x * 16;
    const int which = blockIdx.y;
    const ushort_t* wt = which ? w2tr : w2tl;
    const int l = threadIdx.x;
    const int m = l & 15, q = l >> 4;

    float4v acc[8];
#pragma unroll
    for (int t = 0; t < 8; ++t) acc[t] = (float4v){0.f, 0.f, 0.f, 0.f};

    const ushort_t* arow  = hb + (wrow + m) * HID_DIM + q * 8;
    const ushort_t* bbase = wt + m * 256 + q * 8;

#pragma unroll
    for (int s = 0; s < 8; ++s) {
        short8 a = *(const short8*)(arow + s * 32);
#pragma unroll
        for (int t = 0; t < 8; ++t) {
            short8 b = *(const short8*)(bbase + (t * 16) * 256 + s * 32);
            acc[t] = __builtin_amdgcn_mfma_f32_16x16x32_bf16(a, b, acc[t], 0, 0, 0);
        }
    }

    if (which == 0) {
#pragma unroll
        for (int t = 0; t < 8; ++t) {
            int col = t * 16 + m;
#pragma unroll
            for (int r = 0; r < 4; ++r) {
                int row = wrow + q * 4 + r;
                Pb[row * OUT_DIM + col] = f2bf(acc[t][r]);
            }
        }
    } else {
#pragma unroll
        for (int t = 0; t < 8; ++t) {
            int col = t * 16 + m;
#pragma unroll
            for (int r = 0; r < 4; ++r) {
                int row = wrow + q * 4 + r;
                Rf[row * OUT_DIM + col] = acc[t][r];
            }
        }
    }
}

// ---------------------------------------------------------------------------
// Launch
// ---------------------------------------------------------------------------
extern "C" void kernel_launch(void* const* d_in, const int* in_sizes, int n_in,
                              void* d_out, int out_size, void* d_ws, size_t ws_size,
                              hipStream_t stream) {
    const float* x    = (const float*)d_in[0];
    const int*   ei   = (const int*)  d_in[1];
    const float* W1_l = (const float*)d_in[2];
    const float* b1   = (const float*)d_in[3];
    const float* W1_r = (const float*)d_in[4];
    const float* W2_l = (const float*)d_in[5];
    const float* b2   = (const float*)d_in[6];
    const float* W2_r = (const float*)d_in[7];
    float* out = (float*)d_out;

    const int* src = ei;
    const int* dst = ei + N_EDGES;

    // ---- workspace layout ----
    int* ip     = (int*)d_ws;
    int* deg_i  = ip;                  // 10240
    int* rowptr = ip + 10240;          // 10241 (pad to 10496)
    int* cursor = ip + 20736;          // 10240
    int* esrc   = ip + 30976;          // 640000 -> end 670976 ints
    ushort_t* ub   = (ushort_t*)(ip + 670976);
    ushort_t* xb   = ub;               // 1,280,000
    ushort_t* aggb = ub + 1280000;     // 1,280,000
    ushort_t* w1t  = ub + 2560000;     //    65,536
    ushort_t* w2tl = ub + 2625536;     //    32,768
    ushort_t* w2tr = ub + 2658304;     //    32,768
    ushort_t* hb   = ub + 2691072;     // 2,560,000
    ushort_t* Pb   = ub + 5251072;     // 1,280,000 -> end 6,531,072 ushorts
    float*    Rf   = (float*)(ub + 6531072);   // 1,280,000 floats

    // ---- CSR build + prep ----
    hipMemsetAsync(deg_i, 0, 10240 * sizeof(int), stream);
    prep_kernel<<<(PREP_TOTAL + 255) / 256, 256, 0, stream>>>(
        x, W1_l, W1_r, W2_l, W2_r, xb, w1t, w2tl, w2tr);
    hist_kernel<<<(N_EDGES + 255) / 256, 256, 0, stream>>>(dst, deg_i, N_EDGES);
    scan_kernel<<<1, 256, 0, stream>>>(deg_i, rowptr, cursor, N_NODES);
    fill_kernel<<<(N_EDGES + 255) / 256, 256, 0, stream>>>(src, dst, cursor, esrc, N_EDGES);

    // ---- Layer 1 ----
    gather_mean_bf16<<<N_NODES, 64, 0, stream>>>(xb, rowptr, esrc, aggb);
    mfma1_kernel<<<dim3(625, 2), 64, 0, stream>>>(aggb, xb, w1t, b1, hb);

    // ---- Layer 2 (projection trick + fused epilogue) ----
    mfma2_kernel<<<dim3(625, 2), 64, 0, stream>>>(hb, w2tl, w2tr, Pb, Rf);
    gather_final<<<N_NODES, 64, 0, stream>>>(Pb, rowptr, esrc, Rf, b2, out);
}